// Round 1
// 478.182 us; speedup vs baseline: 1.1258x; 1.1258x over previous
//
#include <hip/hip_runtime.h>
#include <hip/hip_bf16.h>
#include <math.h>

#define HEADS    16
#define HEAD_IN  256
#define HEAD_OUT 1024
#define FULLD    4096
#define BM       128
#define NC       32
#define NCHUNKS  (HEAD_OUT / NC)   // 32
#define THREADS  256
#define LDO      268               // epilogue f32 row stride (dwords): stores 2-way, reads even

typedef short  short8 __attribute__((ext_vector_type(8)));
typedef float  f32x4  __attribute__((ext_vector_type(4)));
typedef float  f32x16 __attribute__((ext_vector_type(16)));
typedef unsigned int u32;

#define AS_GLOBAL __attribute__((address_space(1)))
#define AS_LOCAL  __attribute__((address_space(3)))

__device__ __forceinline__ void gload_lds16(const void* g, void* l) {
    __builtin_amdgcn_global_load_lds((const AS_GLOBAL u32*)g, (AS_LOCAL u32*)l, 16, 0, 0);
}

__device__ __forceinline__ ushort f2bf(float f) {
    union { float f; unsigned u; } x; x.f = f;
    unsigned r = x.u + 0x7fffu + ((x.u >> 16) & 1u);
    return (ushort)(r >> 16);
}

// gelu(v) = v * rcp(1 + exp2(-2.3021254 * (v + 0.044715 v^3)))
__device__ __forceinline__ float fast_gelu(float v) {
    float v2 = v * v;
    float p  = __builtin_fmaf(v2, 0.044715f, 1.0f);
    float a  = v * p * -2.3021254f;
    float e  = __builtin_amdgcn_exp2f(a);
    float r  = __builtin_amdgcn_rcpf(1.0f + e);
    return v * r;
}

// per-head transpose + fp32->bf16 cast: in[h][R][C] fp32 -> out bf16 [h][C][R]
__global__ void __launch_bounds__(256) transpose_head(const float* __restrict__ in,
                                                      ushort* __restrict__ out,
                                                      int R, int C) {
    __shared__ __align__(16) ushort tile[64][68];
    int h = blockIdx.z;
    const float* ip = in  + (size_t)h * R * C;
    ushort*      op = out + (size_t)h * R * C;
    int t  = threadIdx.x;
    int cr = t & 15;
    int rr = t >> 4;
    int r0 = blockIdx.x * 64, c0 = blockIdx.y * 64;
    #pragma unroll
    for (int p = 0; p < 4; ++p) {
        int r = rr + p * 16;
        float4 v = *(const float4*)&ip[(size_t)(r0 + r) * C + c0 + cr * 4];
        tile[r][cr*4+0] = f2bf(v.x); tile[r][cr*4+1] = f2bf(v.y);
        tile[r][cr*4+2] = f2bf(v.z); tile[r][cr*4+3] = f2bf(v.w);
    }
    __syncthreads();
    #pragma unroll
    for (int p = 0; p < 4; ++p) {
        int c = rr + p * 16;
        ushort4 v;
        v.x = tile[cr*4+0][c]; v.y = tile[cr*4+1][c];
        v.z = tile[cr*4+2][c]; v.w = tile[cr*4+3][c];
        *(ushort4*)&op[(size_t)(c0 + c) * R + r0 + cr * 4] = v;
    }
}

// Fused per-head MLP, 32x32x16 bf16 MFMA, swapped-operand stage1 so the GELU
// output is lane-local for stage2 (no intermediate LDS round trip).
// LDS: double-buffered linear tiles, global_load_lds staging, XOR bank swizzle.
//   sW1 buf layout: phys row p(0..31), 16B slot s(0..31):
//       holds W1T[n0 + pi(p)][8*(s ^ (p&7)) .. +7], pi = swap bits 2<->3
//   sW2 buf layout: row d(0..255), 16B slot s(0..3):
//       holds W2T[d][n0 + 8*(s ^ (d&3)) .. +7]
__global__ void __launch_bounds__(THREADS, 2)
fused_mlp(const float* __restrict__ x, const int* __restrict__ perm,
          const ushort* __restrict__ wupT, const float* __restrict__ bup,
          const ushort* __restrict__ wdnT, const float* __restrict__ bdn,
          float* __restrict__ out) {
    __shared__ __align__(16) char smem[2 * 32768];   // [buf][sW1 16KB | sW2 16KB]

    const int t    = threadIdx.x;
    const int wave = t >> 6;          // 0..3, owns rows m0 + wave*32 .. +31
    const int lane = t & 63;
    const int rho  = lane & 31;
    const int h5   = lane >> 5;
    const int h    = blockIdx.y;
    const int m0   = blockIdx.x * BM;

    // ---- staging source pointers (chunk 0) ----
    const ushort* g1b[4];
    const ushort* g2b[4];
    #pragma unroll
    for (int p = 0; p < 4; ++p) {
        int row = p*8 + wave*2 + h5;                               // sW1 phys row
        int n   = (row & 0x13) | ((row & 4) << 1) | ((row & 8) >> 1);  // pi(row)
        g1b[p] = wupT + (((size_t)h*HEAD_OUT + n) << 8) + (rho ^ (row & 7)) * 8;
        int d  = p*64 + wave*16 + (lane >> 2);                     // sW2 row
        g2b[p] = wdnT + (((size_t)h*HEAD_IN + d) << 10) + ((lane & 3) ^ (d & 3)) * 8;
    }
    char* l1b = smem + wave*1024;            // + p*4096 (+ buf)
    char* l2b = smem + 16384 + wave*1024;

    // issue chunk-0 staging into buffer 0
    #pragma unroll
    for (int p = 0; p < 4; ++p) {
        gload_lds16(g1b[p], l1b + p*4096);
        gload_lds16(g2b[p], l2b + p*4096);
    }

    // ---- X preload (bf16), rows m0+wave*32+rho, all K=256 ----
    short8 xf[16];
    {
        const float* xrow = x + (size_t)(m0 + wave*32 + rho) * FULLD;
        #pragma unroll
        for (int ks = 0; ks < 16; ++ks) {
            int g = perm[h*HEAD_IN + ks*16 + h5*8];   // 8-aligned within 64-run
            float4 a = *(const float4*)(xrow + g);
            float4 b = *(const float4*)(xrow + g + 4);
            short8 v;
            v[0]=(short)f2bf(a.x); v[1]=(short)f2bf(a.y);
            v[2]=(short)f2bf(a.z); v[3]=(short)f2bf(a.w);
            v[4]=(short)f2bf(b.x); v[5]=(short)f2bf(b.y);
            v[6]=(short)f2bf(b.z); v[7]=(short)f2bf(b.w);
            xf[ks] = v;
        }
    }

    f32x16 oacc[8];
    #pragma unroll
    for (int i = 0; i < 8; ++i)
        #pragma unroll
        for (int e = 0; e < 16; ++e) oacc[i][e] = 0.f;

    const float* bupb = bup + h*HEAD_OUT + h5*8;
    const int x1 = rho & 7;
    const int x2 = rho & 3;

    __syncthreads();   // drains vmcnt: chunk-0 tiles ready

    for (int ch = 0; ch < NCHUNKS; ++ch) {
        const int buf = (ch & 1) * 32768;

        // prefetch next chunk into the other buffer (overlaps this chunk's compute)
        if (ch + 1 < NCHUNKS) {
            const int nbuf = ((ch + 1) & 1) * 32768;
            const size_t d1 = (size_t)(ch + 1) * (NC * 256);
            const size_t d2 = (size_t)(ch + 1) * NC;
            #pragma unroll
            for (int p = 0; p < 4; ++p) {
                gload_lds16(g1b[p] + d1, l1b + nbuf + p*4096);
                gload_lds16(g2b[p] + d2, l2b + nbuf + p*4096);
            }
        }

        // ---- stage 1 (swapped): T32 = W1chunk^T x X^T, two accumulation chains ----
        const char* s1 = smem + buf + rho*512;
        f32x16 te, to;
        #pragma unroll
        for (int e = 0; e < 16; ++e) { te[e] = 0.f; to[e] = 0.f; }
        #pragma unroll
        for (int ks = 0; ks < 16; ks += 2) {
            short8 w0 = *(const short8*)(s1 + ((((ks    )*2 + h5) ^ x1) * 16));
            short8 w1 = *(const short8*)(s1 + ((((ks + 1)*2 + h5) ^ x1) * 16));
            te = __builtin_amdgcn_mfma_f32_32x32x16_bf16(w0, xf[ks],     te, 0, 0, 0);
            to = __builtin_amdgcn_mfma_f32_32x32x16_bf16(w1, xf[ks + 1], to, 0, 0, 0);
        }

        // ---- bias + gelu + pack: reg 8kk+j holds T[m][n0+16kk+8*h5+j] -> A-frag ----
        short8 a2[2];
        #pragma unroll
        for (int kk = 0; kk < 2; ++kk) {
            f32x4 bA = *(const f32x4*)(bupb + ch*NC + kk*16);
            f32x4 bB = *(const f32x4*)(bupb + ch*NC + kk*16 + 4);
            short8 v;
            #pragma unroll
            for (int e = 0; e < 4; ++e) {
                float u0 = te[kk*8 + e]     + to[kk*8 + e]     + bA[e];
                float u1 = te[kk*8 + 4 + e] + to[kk*8 + 4 + e] + bB[e];
                v[e]     = (short)f2bf(fast_gelu(u0));
                v[4 + e] = (short)f2bf(fast_gelu(u1));
            }
            a2[kk] = v;
        }

        // ---- stage 2: O(32x256) += T32 @ W2chunk(32x256) ----
        const char* s2 = smem + buf + 16384 + rho*64;
        #pragma unroll
        for (int kk = 0; kk < 2; ++kk) {
            #pragma unroll
            for (int dt = 0; dt < 8; ++dt) {
                short8 b = *(const short8*)(s2 + dt*2048 + (((kk*2 + h5) ^ x2) * 16));
                oacc[dt] = __builtin_amdgcn_mfma_f32_32x32x16_bf16(a2[kk], b, oacc[dt], 0, 0, 0);
            }
        }

        __syncthreads();   // all waves done with buf; next-chunk staging drained
    }

    // ---- epilogue: per-quarter LDS transpose + perm-scattered float4 stores ----
    float* sOutF = (float*)smem;   // [32][LDO]
    #pragma unroll
    for (int quar = 0; quar < 4; ++quar) {
        __syncthreads();
        if (wave == quar) {
            #pragma unroll
            for (int dt = 0; dt < 8; ++dt) {
                const float bias = bdn[h*HEAD_IN + dt*32 + rho];
                #pragma unroll
                for (int rg = 0; rg < 16; ++rg) {
                    int row = (rg & 3) + 8*(rg >> 2) + 4*h5;
                    sOutF[row*LDO + dt*32 + rho] = oacc[dt][rg] + bias;
                }
            }
        }
        __syncthreads();
        #pragma unroll
        for (int i = 0; i < 4; ++i) {
            int idx = i*THREADS + t;          // 32 rows x 32 col-segments
            int mr  = idx >> 5;
            int sg  = idx & 31;
            int g   = perm[h*HEAD_IN + sg*8]; // out[:, perm[c]] = h2[:, c]
            const float* src = sOutF + mr*LDO + sg*8;
            float4 v0 = *(const float4*)src;
            float4 v1 = *(const float4*)(src + 4);
            float* dst = out + (size_t)(m0 + quar*32 + mr)*FULLD + g;
            *(float4*)dst       = v0;
            *(float4*)(dst + 4) = v1;
        }
    }
}

extern "C" void kernel_launch(void* const* d_in, const int* in_sizes, int n_in,
                              void* d_out, int out_size, void* d_ws, size_t ws_size,
                              hipStream_t stream) {
    const float* x    = (const float*)d_in[0];
    const int*   perm = (const int*)d_in[1];
    const float* wup  = (const float*)d_in[2];
    const float* bup  = (const float*)d_in[3];
    const float* wdn  = (const float*)d_in[4];
    const float* bdn  = (const float*)d_in[5];
    float* out = (float*)d_out;

    const int Bt = in_sizes[0] / FULLD;               // 8192
    const size_t wcount = (size_t)HEADS * HEAD_IN * HEAD_OUT;

    ushort* wupT = (ushort*)d_ws;                     // bf16 W1^T: 8 MB
    ushort* wdnT = wupT + wcount;                     // bf16 W2^T: 8 MB

    transpose_head<<<dim3(HEAD_IN/64,  HEAD_OUT/64, HEADS), 256, 0, stream>>>(wup, wupT, HEAD_IN,  HEAD_OUT);
    transpose_head<<<dim3(HEAD_OUT/64, HEAD_IN/64,  HEADS), 256, 0, stream>>>(wdn, wdnT, HEAD_OUT, HEAD_IN);

    dim3 grid(Bt / BM, HEADS, 1);
    fused_mlp<<<grid, THREADS, 0, stream>>>(x, perm, wupT, bup, wdnT, bdn, out);
}

// Round 2
// 472.641 us; speedup vs baseline: 1.1390x; 1.0117x over previous
//
#include <hip/hip_runtime.h>
#include <hip/hip_bf16.h>
#include <math.h>

#define HEADS    16
#define HEAD_IN  256
#define HEAD_OUT 1024
#define FULLD    4096
#define BM       256
#define NC       32
#define NCHUNKS  (HEAD_OUT / NC)   // 32
#define THREADS  512
#define LDO      268               // epilogue f32 row stride (dwords)
#define BUFSZ    32768             // per-chunk weight tile: sW1 16KB + sW2 16KB

typedef short  short8 __attribute__((ext_vector_type(8)));
typedef float  f32x4  __attribute__((ext_vector_type(4)));
typedef float  f32x16 __attribute__((ext_vector_type(16)));
typedef unsigned int u32;

#define AS_GLOBAL __attribute__((address_space(1)))
#define AS_LOCAL  __attribute__((address_space(3)))

__device__ __forceinline__ void gload_lds16(const void* g, void* l) {
    __builtin_amdgcn_global_load_lds((const AS_GLOBAL u32*)g, (AS_LOCAL u32*)l, 16, 0, 0);
}

__device__ __forceinline__ ushort f2bf(float f) {
    union { float f; unsigned u; } x; x.f = f;
    unsigned r = x.u + 0x7fffu + ((x.u >> 16) & 1u);
    return (ushort)(r >> 16);
}

// gelu(v) = v * rcp(1 + exp2(-2.3021254 * (v + 0.044715 v^3)))
__device__ __forceinline__ float fast_gelu(float v) {
    float v2 = v * v;
    float p  = __builtin_fmaf(v2, 0.044715f, 1.0f);
    float a  = v * p * -2.3021254f;
    float e  = __builtin_amdgcn_exp2f(a);
    float r  = __builtin_amdgcn_rcpf(1.0f + e);
    return v * r;
}

// per-head transpose + fp32->bf16 cast: in[h][R][C] fp32 -> out bf16 [h][C][R]
__global__ void __launch_bounds__(256) transpose_head(const float* __restrict__ in,
                                                      ushort* __restrict__ out,
                                                      int R, int C) {
    __shared__ __align__(16) ushort tile[64][68];
    int h = blockIdx.z;
    const float* ip = in  + (size_t)h * R * C;
    ushort*      op = out + (size_t)h * R * C;
    int t  = threadIdx.x;
    int cr = t & 15;
    int rr = t >> 4;
    int r0 = blockIdx.x * 64, c0 = blockIdx.y * 64;
    #pragma unroll
    for (int p = 0; p < 4; ++p) {
        int r = rr + p * 16;
        float4 v = *(const float4*)&ip[(size_t)(r0 + r) * C + c0 + cr * 4];
        tile[r][cr*4+0] = f2bf(v.x); tile[r][cr*4+1] = f2bf(v.y);
        tile[r][cr*4+2] = f2bf(v.z); tile[r][cr*4+3] = f2bf(v.w);
    }
    __syncthreads();
    #pragma unroll
    for (int p = 0; p < 4; ++p) {
        int c = rr + p * 16;
        ushort4 v;
        v.x = tile[cr*4+0][c]; v.y = tile[cr*4+1][c];
        v.z = tile[cr*4+2][c]; v.w = tile[cr*4+3][c];
        *(ushort4*)&op[(size_t)(c0 + c) * R + r0 + cr * 4] = v;
    }
}

// Fused per-head MLP, 32x32x16 bf16 MFMA, swapped-operand stage1 (GELU output
// lane-local for stage2). 1 block/CU, 8 waves (register-capped at 2 waves/SIMD).
// Weight tiles stream via global_load_lds into a 3-buffer ring, prefetch
// distance 2, counted vmcnt(4) + raw s_barrier per chunk (never drain to 0).
//   sW1 buf: phys row p(0..31), slot s(0..31): W1T[n0+pi(p)][8*(s^(p&7))..+7],
//            pi = swap bits 2<->3
//   sW2 buf: row d(0..255), slot s(0..3): W2T[d][n0 + 8*(s ^ ((d>>1)&3))..+7]
__global__ void __launch_bounds__(THREADS, 2)
fused_mlp(const float* __restrict__ x, const int* __restrict__ perm,
          const ushort* __restrict__ wupT, const float* __restrict__ bup,
          const ushort* __restrict__ wdnT, const float* __restrict__ bdn,
          float* __restrict__ out) {
    __shared__ __align__(16) char smem[3 * BUFSZ];   // 96 KB

    const int t    = threadIdx.x;
    const int wave = t >> 6;          // 0..7, owns rows m0 + wave*32 .. +31
    const int lane = t & 63;
    const int rho  = lane & 31;
    const int h5   = lane >> 5;

    // XCD swizzle: 512 blocks = 64/XCD = 2 heads x 32 m-tiles per XCD L2
    const int bflat = blockIdx.x + (blockIdx.y << 5);   // grid (32,16)
    const int xcd   = bflat & 7;
    const int bidx  = bflat >> 3;                       // 0..63
    const int h     = xcd * 2 + (bidx >> 5);
    const int m0    = (bidx & 31) * BM;

    // ---- staging source pointers / LDS dest offsets (chunk 0) ----
    const ushort* g1s[2];
    const ushort* g2s[2];
    #pragma unroll
    for (int a = 0; a < 2; ++a) {
        int j = a * THREADS + t;                 // 0..1023 16B slots
        int p = j >> 5, s = j & 31;              // sW1 phys row / slot
        int n = (p & 0x13) | ((p & 4) << 1) | ((p & 8) >> 1);   // pi(p)
        g1s[a] = wupT + (((size_t)h * HEAD_OUT + n) << 8) + (s ^ (p & 7)) * 8;
        int d = j >> 2, sq = j & 3;              // sW2 row / slot
        g2s[a] = wdnT + (((size_t)h * HEAD_IN + d) << 10) + (sq ^ ((d >> 1) & 3)) * 8;
    }
    char* l1d = smem + wave * 1024;              // + a*8192 (+ buf)
    char* l2d = smem + 16384 + wave * 1024;

    // prologue: issue P0 -> buf0, P1 -> buf1 (4 issues each, strict order)
    #pragma unroll
    for (int a = 0; a < 2; ++a) {
        gload_lds16(g1s[a], l1d + a * 8192);
        gload_lds16(g2s[a], l2d + a * 8192);
    }
    #pragma unroll
    for (int a = 0; a < 2; ++a) {
        gload_lds16(g1s[a] + (size_t)NC * 256, l1d + BUFSZ + a * 8192);
        gload_lds16(g2s[a] + NC,               l2d + BUFSZ + a * 8192);
    }

    // ---- X preload (bf16), rows m0+wave*32+rho, all K=256 ----
    short8 xf[16];
    {
        const float* xrow = x + (size_t)(m0 + wave * 32 + rho) * FULLD;
        #pragma unroll
        for (int ks = 0; ks < 16; ++ks) {
            int g = perm[h * HEAD_IN + ks * 16 + h5 * 8];  // 8-aligned in 64-run
            float4 a = *(const float4*)(xrow + g);
            float4 b = *(const float4*)(xrow + g + 4);
            short8 v;
            v[0]=(short)f2bf(a.x); v[1]=(short)f2bf(a.y);
            v[2]=(short)f2bf(a.z); v[3]=(short)f2bf(a.w);
            v[4]=(short)f2bf(b.x); v[5]=(short)f2bf(b.y);
            v[6]=(short)f2bf(b.z); v[7]=(short)f2bf(b.w);
            xf[ks] = v;
        }
    }

    f32x16 oacc[8];
    #pragma unroll
    for (int i = 0; i < 8; ++i)
        #pragma unroll
        for (int e = 0; e < 16; ++e) oacc[i][e] = 0.f;

    const float* bupb = bup + h * HEAD_OUT + h5 * 8;
    const int x1 = rho & 7;
    const int x2 = (rho >> 1) & 3;

    int cur = 0;   // byte offset of current ring buffer
    for (int ch = 0; ch < NCHUNKS; ++ch) {
        // own P(ch) landed (P(ch+1) stays in flight); then all-waves barrier:
        // after it, every wave's P(ch) portion is in LDS and all waves are done
        // reading buf[(ch-1)%3] (so P(ch+2) may overwrite it).
        asm volatile("s_waitcnt vmcnt(4)\n\ts_barrier" ::: "memory");

        // issue P(ch+2) into buf[(ch+2)%3]; tail issues clamped dummies so the
        // vmcnt(4) count stays uniform (dummy dests are dead buffers).
        {
            int cc = ch + 2 < NCHUNKS ? ch + 2 : NCHUNKS - 1;
            int pf = cur - BUFSZ; if (pf < 0) pf += 3 * BUFSZ;   // (cur+2)%3
            #pragma unroll
            for (int a = 0; a < 2; ++a) {
                gload_lds16(g1s[a] + (size_t)cc * (NC * 256), l1d + pf + a * 8192);
                gload_lds16(g2s[a] + (size_t)cc * NC,         l2d + pf + a * 8192);
            }
        }

        // ---- stage 1 (swapped): T32 = W1chunk^T x X^T ----
        const char* s1 = smem + cur + rho * 512;
        f32x16 te, to;
        #pragma unroll
        for (int e = 0; e < 16; ++e) { te[e] = 0.f; to[e] = 0.f; }
        __builtin_amdgcn_s_setprio(1);
        #pragma unroll
        for (int ks = 0; ks < 16; ks += 2) {
            short8 w0 = *(const short8*)(s1 + ((((ks    ) * 2 + h5) ^ x1) * 16));
            short8 w1 = *(const short8*)(s1 + ((((ks + 1) * 2 + h5) ^ x1) * 16));
            te = __builtin_amdgcn_mfma_f32_32x32x16_bf16(w0, xf[ks],     te, 0, 0, 0);
            to = __builtin_amdgcn_mfma_f32_32x32x16_bf16(w1, xf[ks + 1], to, 0, 0, 0);
        }
        __builtin_amdgcn_s_setprio(0);

        // ---- bias + gelu + pack: reg 8kk+j = T[m][n0+16kk+8h5+j] -> A-frag ----
        short8 a2[2];
        #pragma unroll
        for (int kk = 0; kk < 2; ++kk) {
            f32x4 bA = *(const f32x4*)(bupb + ch * NC + kk * 16);
            f32x4 bB = *(const f32x4*)(bupb + ch * NC + kk * 16 + 4);
            short8 v;
            #pragma unroll
            for (int e = 0; e < 4; ++e) {
                float u0 = te[kk*8 + e]     + to[kk*8 + e]     + bA[e];
                float u1 = te[kk*8 + 4 + e] + to[kk*8 + 4 + e] + bB[e];
                v[e]     = (short)f2bf(fast_gelu(u0));
                v[4 + e] = (short)f2bf(fast_gelu(u1));
            }
            a2[kk] = v;
        }

        // ---- stage 2: O(32x256) += T32 @ W2chunk(32x256) ----
        const char* s2 = smem + cur + 16384 + rho * 64;
        __builtin_amdgcn_s_setprio(1);
        #pragma unroll
        for (int kk = 0; kk < 2; ++kk) {
            #pragma unroll
            for (int dt = 0; dt < 8; ++dt) {
                short8 b = *(const short8*)(s2 + dt * 2048 + (((kk * 2 + h5) ^ x2) * 16));
                oacc[dt] = __builtin_amdgcn_mfma_f32_32x32x16_bf16(a2[kk], b, oacc[dt], 0, 0, 0);
            }
        }
        __builtin_amdgcn_s_setprio(0);

        cur += BUFSZ; if (cur == 3 * BUFSZ) cur = 0;
    }

    __syncthreads();   // full drain (incl. dummy prefetches) before smem reuse

    // ---- epilogue: 4 rounds, 2 waves write 64 rows, then perm-scatter ----
    float* sOutF = (float*)smem;   // [64][LDO] f32 = 68.6 KB <= 96 KB
    #pragma unroll
    for (int ro = 0; ro < 4; ++ro) {
        if (ro) __syncthreads();
        if ((wave >> 1) == ro) {
            const int wl = wave & 1;
            #pragma unroll
            for (int dt = 0; dt < 8; ++dt) {
                const float bias = bdn[h * HEAD_IN + dt * 32 + rho];
                #pragma unroll
                for (int rg = 0; rg < 16; ++rg) {
                    int row = wl * 32 + (rg & 3) + 8 * (rg >> 2) + 4 * h5;
                    sOutF[row * LDO + dt * 32 + rho] = oacc[dt][rg] + bias;
                }
            }
        }
        __syncthreads();
        #pragma unroll
        for (int i = 0; i < 4; ++i) {
            int idx = i * THREADS + t;          // 0..2047 = 64 rows x 32 segs
            int mr  = idx >> 5;
            int sg  = idx & 31;
            int g   = perm[h * HEAD_IN + sg * 8];   // out[:, perm[c]] = h2[:, c]
            const float* src = sOutF + mr * LDO + sg * 8;
            float4 v0 = *(const float4*)src;
            float4 v1 = *(const float4*)(src + 4);
            float* dst = out + (size_t)(m0 + ro * 64 + mr) * FULLD + g;
            *(float4*)dst       = v0;
            *(float4*)(dst + 4) = v1;
        }
    }
}

extern "C" void kernel_launch(void* const* d_in, const int* in_sizes, int n_in,
                              void* d_out, int out_size, void* d_ws, size_t ws_size,
                              hipStream_t stream) {
    const float* x    = (const float*)d_in[0];
    const int*   perm = (const int*)d_in[1];
    const float* wup  = (const float*)d_in[2];
    const float* bup  = (const float*)d_in[3];
    const float* wdn  = (const float*)d_in[4];
    const float* bdn  = (const float*)d_in[5];
    float* out = (float*)d_out;

    const int Bt = in_sizes[0] / FULLD;               // 8192
    const size_t wcount = (size_t)HEADS * HEAD_IN * HEAD_OUT;

    ushort* wupT = (ushort*)d_ws;                     // bf16 W1^T: 8 MB
    ushort* wdnT = wupT + wcount;                     // bf16 W2^T: 8 MB

    transpose_head<<<dim3(HEAD_IN/64,  HEAD_OUT/64, HEADS), 256, 0, stream>>>(wup, wupT, HEAD_IN,  HEAD_OUT);
    transpose_head<<<dim3(HEAD_OUT/64, HEAD_IN/64,  HEADS), 256, 0, stream>>>(wdn, wdnT, HEAD_OUT, HEAD_IN);

    dim3 grid(Bt / BM, HEADS, 1);
    fused_mlp<<<grid, THREADS, 0, stream>>>(x, perm, wupT, bup, wdnT, bdn, out);
}